// Round 1
// baseline (12.262 us; speedup 1.0000x reference)
//
#include <hip/hip_runtime.h>
#include <math.h>

// ============================================================================
// R14: coalesced float4 global->LDS DMA staging (global_load_lds width=16)
// replacing R13's 9x scattered-8B per-lane pooling loads. Theory: R13 is
// vector-memory TRANSACTION bound (9 instr x 64 lanes scattered over ~32
// cache lines each = ~4600 line-touches/CU for 86KB payload). Now each block
// streams its 32 images' 24 used rows (2688 B each, tails skipped) as
// 84 x 1024B lane-linear DMA bursts; pooling gather moves to LDS
// (ds_read_b64, ~4-way conflict, ~0.4us). Table build (waves 0-3) overlaps
// the DMA in-flight window; extra 4 DMA slots go to waves 12-15 to keep
// builders light. Single barrier. Eval path unchanged (R12-proven,
// absmax 0.0156).
// ============================================================================

__device__ __forceinline__ float bpermf(int addr_bytes, float v) {
    return __int_as_float(__builtin_amdgcn_ds_bpermute(addr_bytes, __float_as_int(v)));
}
__device__ __forceinline__ unsigned bpermu(int addr_bytes, unsigned v) {
    return (unsigned)__builtin_amdgcn_ds_bpermute(addr_bytes, (int)v);
}

template<int CTRL>
__device__ __forceinline__ float dppf(float x) {
    return __int_as_float(__builtin_amdgcn_mov_dpp(__float_as_int(x), CTRL, 0xF, 0xF, true));
}

// async global->LDS DMA: dest is wave-uniform base + lane*16 (HW rule),
// global src is per-lane. size must be a literal.
__device__ __forceinline__ void gload_lds16(const float* g, float* l) {
    __builtin_amdgcn_global_load_lds(
        (const __attribute__((address_space(1))) void*)g,
        (__attribute__((address_space(3))) void*)l,
        16, 0, 0);
}

// CNOT(c,t) Pauli conjugation, packed LUTs, idx = pc*4+pt (I X Y Z = 0 1 2 3)
#define NPC_PK 0x0F5AA5F0u
#define NPT_PK 0xE4B1B1E4u
#define NSG_PK 0x00000480u

__global__ __launch_bounds__(1024, 4) void qnet_one(
    const float* __restrict__ x_image,   // [bsz,1,28,28]
    const float* __restrict__ theta_rot, // [2,8,3]
    const int*   __restrict__ hardwts,   // [8,9]
    float*       __restrict__ out,       // [bsz,8]
    int bsz)
{
    // 32 images x 672 floats (24 rows x 28 cols) = 86016 B, + 1KB tables
    __shared__ __align__(16) float    ldsimg[32 * 672];
    __shared__ __align__(16) float    tabF[8][16];
    __shared__ __align__(16) unsigned tabU[8][16];

    const int tid  = threadIdx.x;
    const int lane = tid & 63;
    const int wid  = tid >> 6;           // 0..15
    const int sub  = lane & 31;
    const int hb   = lane >> 5;          // which half = which image of the pair
    const int hof  = lane & 32;          // half offset for shfl sources
    const int bidx = blockIdx.x * 32 + wid * 2 + hb;

    // ---- coalesced DMA: slot g covers float4s [g*64, g*64+64) of the
    //      block's 32-image stream (image i = s/168, float4 j = s%168) ----
    {
        const int base = blockIdx.x * 32;
#pragma unroll
        for (int k = 0; k < 5; ++k) {
            const int g = wid + 16 * k;          // 0..79, wave-uniform
            const int s = g * 64 + lane;
            const int i = s / 168;               // image in block (0..31)
            const int j = s - i * 168;           // float4 within image
            int gi = base + i; if (gi >= bsz) gi = bsz - 1;
            gload_lds16(x_image + (size_t)gi * 784 + (j << 2),
                        &ldsimg[g << 8]);        // uniform LDS base per instr
        }
        if (wid >= 12) {                         // slots 80..83 (not builders)
            const int g = wid + 68;
            const int s = g * 64 + lane;
            const int i = s / 168;
            const int j = s - i * 168;
            int gi = base + i; if (gi >= bsz) gi = bsz - 1;
            gload_lds16(x_image + (size_t)gi * 784 + (j << 2),
                        &ldsimg[g << 8]);
        }
    }

    if (wid < 4) {
        // ---- builders: table build overlaps the in-flight DMA ----
        // op selection per wire (wave-uniform scalar work)
        int ksel[8];
#pragma unroll
        for (int j = 0; j < 8; ++j) {
            int base = j * 9;
            int best = hardwts[base], k = 0;
#pragma unroll
            for (int kk = 1; kk <= 8; ++kk) {
                int v = hardwts[base + kk];
                if (v > best) { best = v; k = kk; }
            }
            ksel[j] = k;
        }

        // table build (R12-proven): group = one obs, slot = lane&31
        const int grp  = lane >> 5;
        const int obs  = (wid << 1) | grp;   // 0..7 across waves 0-3
        const int slot = sub;
        const int s3   = slot / 3;
        const int w3   = slot - 3 * s3;
        const int paddr = (s3 + hof) << 2;

        float    cf = (slot == 0) ? 1.f : 0.f;
        unsigned cd = (slot == 0) ? (3u << (2 * obs)) : 0u;
        int cnt = 1;

#pragma unroll 1
        for (int step = 0; step < 16; ++step) {
            const int layer = (step < 8) ? 1 : 0;
            const int j = 7 - (step & 7);
            int k = ksel[j];                 // wave-uniform
            if (k == 8) {
                int pred = ((cd >> (2 * j)) & 3) != 0;
                unsigned long long bal = __ballot(pred);
                unsigned myhalf = (unsigned)(bal >> hof);
                if (myhalf != 0) {           // group-uniform branch
                    float t0 = theta_rot[layer*24 + j*3 + 0];
                    float t1 = theta_rot[layer*24 + j*3 + 1];
                    float t2 = theta_rot[layer*24 + j*3 + 2];
                    float c0 = __cosf(t0), s0 = __sinf(t0);
                    float c1 = __cosf(t1), s1 = __sinf(t1);
                    float c2 = __cosf(t2), s2 = __sinf(t2);
                    float    pcf = bpermf(paddr, cf);
                    unsigned pcd = bpermu(paddr, cd);
                    int p = (pcd >> (2 * j)) & 3;
                    bool valid = (s3 < cnt);
                    float cx = (p == 1) ? 1.f : 0.f;
                    float cy = (p == 2) ? 1.f : 0.f;
                    float cz = (p == 3) ? 1.f : 0.f;
                    { float nx = cx*c2 + cy*s2, ny = cy*c2 - cx*s2; cx = nx; cy = ny; } // RZ(t2)
                    { float nx = cx*c1 - cz*s1, nz = cx*s1 + cz*c1; cx = nx; cz = nz; } // RY(t1)
                    { float nx = cx*c0 + cy*s0, ny = cy*c0 - cx*s0; cx = nx; cy = ny; } // RZ(t0)
                    float comp = (w3 == 0) ? cx : (w3 == 1) ? cy : cz;
                    unsigned base2   = pcd & ~(3u << (2 * j));
                    unsigned ncd_rot = base2 | ((unsigned)(w3 + 1) << (2 * j));
                    float    ncf_rot = pcf * comp;
                    bool  isI  = (p == 0);
                    float    ncf0 = (w3 == 0) ? pcf : 0.f;
                    unsigned ncd0 = (w3 == 0) ? pcd : 0u;
                    cf = valid ? (isI ? ncf0 : ncf_rot) : 0.f;
                    cd = valid ? (isI ? ncd0 : ncd_rot) : 0u;
                    cnt = (3 * cnt > 32) ? 32 : 3 * cnt;
                }
            } else if (k != j) {
                int pc = (cd >> (2 * j)) & 3;
                int pt = (cd >> (2 * k)) & 3;
                int idx = pc * 4 + pt;
                unsigned npc = (NPC_PK >> (2 * idx)) & 3u;
                unsigned npt = (NPT_PK >> (2 * idx)) & 3u;
                cd = (cd & ~((3u << (2 * j)) | (3u << (2 * k))))
                     | (npc << (2 * j)) | (npt << (2 * k));
                cf = ((NSG_PK >> idx) & 1u) ? -cf : cf;
            }
        }

        if (slot < 16) { tabF[obs][slot] = cf; tabU[obs][slot] = cd; }
    }

    __syncthreads();   // drains DMA (vmcnt) + publishes tables

    // ---- pooling gather from LDS (ds_read_b64, ~4-way conflict) ----
    const float* ip = &ldsimg[(wid * 2 + hb) * 672];
    const int cell = sub & 15, rh4 = sub >> 4;
    const int ry = cell >> 2, rx = cell & 3;
    float sum = 0.f;
#pragma unroll
    for (int rr = 0; rr < 3; ++rr) {
        const float* rp = ip + (ry * 6 + rh4 * 3 + rr) * 28 + rx * 6;
#pragma unroll
        for (int cc = 0; cc < 3; ++cc) {
            float2 v = *reinterpret_cast<const float2*>(rp + 2 * cc);
            sum += v.x + v.y;
        }
    }
    sum += __shfl_xor(sum, 16, 64);      // merge row-halves (stays in half)
    float ang = sum * (1.0f / 36.0f);    // full pooled angle
    float s_a = __sinf(ang), c_a = __cosf(ang);
    float sbp = dppf<0xB1>(s_a);
    float cbp = dppf<0xB1>(c_a);
    float bx = s_a * cbp;                // sin a cos b
    float by = s_a * sbp;                // sin a sin b
    float bz = c_a;                      // cos a
    float Xc[8], Yc[8], Zc[8];
#pragma unroll
    for (int j = 0; j < 8; ++j) {
        int src = hof + 2 * j;
        Xc[j] = __shfl(bx, src, 64);
        Yc[j] = __shfl(by, src, 64);
        Zc[j] = __shfl(bz, src, 64);
    }

    // ---- term eval: w = sub>>2 (obs), ls = sub&3; slots ls*4 .. ls*4+3 ----
    const int w = (sub >> 2) & 7, ls = sub & 3;
    float4 cf4 = *reinterpret_cast<const float4*>(&tabF[w][ls * 4]);
    uint4  cd4 = *reinterpret_cast<const uint4 *>(&tabU[w][ls * 4]);
    const float    cfa[4] = { cf4.x, cf4.y, cf4.z, cf4.w };
    const unsigned cda[4] = { cd4.x, cd4.y, cd4.z, cd4.w };

    float acc = 0.f;
#pragma unroll
    for (int kslot = 0; kslot < 4; ++kslot) {
        float p = cfa[kslot];
        unsigned code = cda[kslot];
#define APPLY(J) { int s_ = (int)((code >> (2*J)) & 3u); \
    float f_ = 1.0f; f_ = (s_==1) ? Xc[J] : f_; f_ = (s_==2) ? Yc[J] : f_; \
    f_ = (s_==3) ? Zc[J] : f_;  p *= f_; }
        APPLY(0) APPLY(1) APPLY(2) APPLY(3) APPLY(4) APPLY(5) APPLY(6) APPLY(7)
#undef APPLY
        acc += p;
    }

    // reduce over the 4 slot-lanes (sub bits 0,1) on the VALU pipe
    acc += dppf<0xB1>(acc);
    acc += dppf<0x4E>(acc);
    float ev = acc;                      // all 4 slot-lanes of (half,w) hold ev[w]

    // ---- max-free log_softmax across the 8 observables (sub bits 2,3,4) ----
    // |ev| <= sum|coef| <= 3 (SO(3) rows, <=2 rot expansions) => exp in [.05,20]
    float e  = __expf(ev);
    float se = e;
    se += __shfl_xor(se, 4, 64);
    se += __shfl_xor(se, 8, 64);
    se += __shfl_xor(se, 16, 64);
    float res = ev - __logf(se);

    if (ls == 0 && bidx < bsz)
        out[(size_t)bidx * 8 + w] = res;
}

extern "C" void kernel_launch(void* const* d_in, const int* in_sizes, int n_in,
                              void* d_out, int out_size, void* d_ws, size_t ws_size,
                              hipStream_t stream) {
    const float* x_image   = (const float*)d_in[0];
    const float* theta_rot = (const float*)d_in[1];
    const int*   hardwts   = (const int*)d_in[2];
    float*       out       = (float*)d_out;
    int bsz = in_sizes[0] / 784;   // 8192
    hipLaunchKernelGGL(qnet_one, dim3((bsz + 31) / 32), dim3(1024), 0, stream,
                       x_image, theta_rot, hardwts, out, bsz);
}

// Round 2
// 11.716 us; speedup vs baseline: 1.0466x; 1.0466x over previous
//
#include <hip/hip_runtime.h>
#include <math.h>

// ============================================================================
// R15 = R13 restored (best proven: 11.63 us). R14's coalesced global->LDS DMA
// staging REGRESSED (+0.6 us): the scattered pooling loads were never the
// bottleneck (transaction theory falsified), and the staging barrier drains
// vmcnt(0) for all 84 block-wide DMAs before any wave proceeds.
// Heisenberg-picture, SINGLE dispatch, 256 WGs x 1024 threads, 4 waves/SIMD,
// table build by waves 0-3 (amortized over 16 waves); other 12 waves finish
// pooling/Bloch BEFORE the barrier. Max-free log_softmax. Eval path proven
// (absmax 0.0156).
// Floor analysis: compulsory read 22-26 MB @6.3 TB/s ~= 3.5-4 us + ~0.5-1 us
// VALU/DS; measured 11.6 across R12/R13/R14 structural variants => remaining
// ~7 us is dispatch/graph overhead + short-burst HBM ramp, invariant to
// kernel internals.
// ============================================================================

__device__ __forceinline__ float bpermf(int addr_bytes, float v) {
    return __int_as_float(__builtin_amdgcn_ds_bpermute(addr_bytes, __float_as_int(v)));
}
__device__ __forceinline__ unsigned bpermu(int addr_bytes, unsigned v) {
    return (unsigned)__builtin_amdgcn_ds_bpermute(addr_bytes, (int)v);
}

template<int CTRL>
__device__ __forceinline__ float dppf(float x) {
    return __int_as_float(__builtin_amdgcn_mov_dpp(__float_as_int(x), CTRL, 0xF, 0xF, true));
}

// CNOT(c,t) Pauli conjugation, packed LUTs, idx = pc*4+pt (I X Y Z = 0 1 2 3)
#define NPC_PK 0x0F5AA5F0u
#define NPT_PK 0xE4B1B1E4u
#define NSG_PK 0x00000480u

// pooling-finish + Bloch + per-half gather (pure wave-local, no LDS storage)
__device__ __forceinline__ void bloch_gather(const float2 pv[9], int hof,
                                             float Xc[8], float Yc[8], float Zc[8]) {
    float sum = 0.f;
#pragma unroll
    for (int q = 0; q < 9; ++q) sum += pv[q].x + pv[q].y;
    sum += __shfl_xor(sum, 16, 64);      // merge row-halves (stays in half)
    float ang = sum * (1.0f / 36.0f);    // full pooled angle
    float s_a = __sinf(ang), c_a = __cosf(ang);
    // Bloch on even-sub lanes (cell 2j = a_j, cell 2j+1 = b_j)
    float sbp = dppf<0xB1>(s_a);
    float cbp = dppf<0xB1>(c_a);
    float bx = s_a * cbp;                // sin a cos b
    float by = s_a * sbp;                // sin a sin b
    float bz = c_a;                      // cos a
#pragma unroll
    for (int j = 0; j < 8; ++j) {
        int src = hof + 2 * j;
        Xc[j] = __shfl(bx, src, 64);
        Yc[j] = __shfl(by, src, 64);
        Zc[j] = __shfl(bz, src, 64);
    }
}

__global__ __launch_bounds__(1024, 4) void qnet_one(
    const float* __restrict__ x_image,   // [bsz,1,28,28]
    const float* __restrict__ theta_rot, // [2,8,3]
    const int*   __restrict__ hardwts,   // [8,9]
    float*       __restrict__ out,       // [bsz,8]
    int bsz)
{
    __shared__ __align__(16) float    tabF[8][16];
    __shared__ __align__(16) unsigned tabU[8][16];

    const int tid  = threadIdx.x;
    const int lane = tid & 63;
    const int wid  = tid >> 6;           // 0..15
    const int sub  = lane & 31;
    const int hb   = lane >> 5;          // which half = which element
    const int hof  = lane & 32;          // half offset for shfl sources
    int bidx = blockIdx.x * 32 + wid * 2 + hb;
    int bidxc = bidx < bsz ? bidx : bsz - 1;
    const float* img = x_image + (size_t)bidxc * 784;

    // ---- issue pooling loads FIRST (latency hides under build / finish) ----
    const int cell = sub & 15, rh4 = sub >> 4;
    const int ry = cell >> 2, rx = cell & 3;
    float2 pv[9];
#pragma unroll
    for (int rr = 0; rr < 3; ++rr) {
        const float* rp = img + (ry * 6 + rh4 * 3 + rr) * 28 + rx * 6;
#pragma unroll
        for (int cc = 0; cc < 3; ++cc)
            pv[rr * 3 + cc] = *reinterpret_cast<const float2*>(rp + 2 * cc);
    }

    float Xc[8], Yc[8], Zc[8];
    const bool builder = (wid < 4);

    if (builder) {
        // ---- op selection per wire (wave-uniform scalar work) ----
        int ksel[8];
#pragma unroll
        for (int j = 0; j < 8; ++j) {
            int base = j * 9;
            int best = hardwts[base], k = 0;
#pragma unroll
            for (int kk = 1; kk <= 8; ++kk) {
                int v = hardwts[base + kk];
                if (v > best) { best = v; k = kk; }
            }
            ksel[j] = k;
        }

        // ---- table build (R12-proven): group = one obs, slot = lane&31 ----
        const int grp  = lane >> 5;
        const int obs  = (wid << 1) | grp;   // 0..7 across waves 0-3
        const int slot = sub;
        const int s3   = slot / 3;
        const int w3   = slot - 3 * s3;
        const int paddr = (s3 + hof) << 2;

        float    cf = (slot == 0) ? 1.f : 0.f;
        unsigned cd = (slot == 0) ? (3u << (2 * obs)) : 0u;
        int cnt = 1;

#pragma unroll 1
        for (int step = 0; step < 16; ++step) {
            const int layer = (step < 8) ? 1 : 0;
            const int j = 7 - (step & 7);
            int k = ksel[j];                 // wave-uniform
            if (k == 8) {
                int pred = ((cd >> (2 * j)) & 3) != 0;
                unsigned long long bal = __ballot(pred);
                unsigned myhalf = (unsigned)(bal >> hof);
                if (myhalf != 0) {           // group-uniform branch
                    float t0 = theta_rot[layer*24 + j*3 + 0];
                    float t1 = theta_rot[layer*24 + j*3 + 1];
                    float t2 = theta_rot[layer*24 + j*3 + 2];
                    float c0 = __cosf(t0), s0 = __sinf(t0);
                    float c1 = __cosf(t1), s1 = __sinf(t1);
                    float c2 = __cosf(t2), s2 = __sinf(t2);
                    float    pcf = bpermf(paddr, cf);
                    unsigned pcd = bpermu(paddr, cd);
                    int p = (pcd >> (2 * j)) & 3;
                    bool valid = (s3 < cnt);
                    float cx = (p == 1) ? 1.f : 0.f;
                    float cy = (p == 2) ? 1.f : 0.f;
                    float cz = (p == 3) ? 1.f : 0.f;
                    { float nx = cx*c2 + cy*s2, ny = cy*c2 - cx*s2; cx = nx; cy = ny; } // RZ(t2)
                    { float nx = cx*c1 - cz*s1, nz = cx*s1 + cz*c1; cx = nx; cz = nz; } // RY(t1)
                    { float nx = cx*c0 + cy*s0, ny = cy*c0 - cx*s0; cx = nx; cy = ny; } // RZ(t0)
                    float comp = (w3 == 0) ? cx : (w3 == 1) ? cy : cz;
                    unsigned base2   = pcd & ~(3u << (2 * j));
                    unsigned ncd_rot = base2 | ((unsigned)(w3 + 1) << (2 * j));
                    float    ncf_rot = pcf * comp;
                    bool  isI  = (p == 0);
                    float    ncf0 = (w3 == 0) ? pcf : 0.f;
                    unsigned ncd0 = (w3 == 0) ? pcd : 0u;
                    cf = valid ? (isI ? ncf0 : ncf_rot) : 0.f;
                    cd = valid ? (isI ? ncd0 : ncd_rot) : 0u;
                    cnt = (3 * cnt > 32) ? 32 : 3 * cnt;
                }
            } else if (k != j) {
                int pc = (cd >> (2 * j)) & 3;
                int pt = (cd >> (2 * k)) & 3;
                int idx = pc * 4 + pt;
                unsigned npc = (NPC_PK >> (2 * idx)) & 3u;
                unsigned npt = (NPT_PK >> (2 * idx)) & 3u;
                cd = (cd & ~((3u << (2 * j)) | (3u << (2 * k))))
                     | (npc << (2 * j)) | (npt << (2 * k));
                cf = ((NSG_PK >> idx) & 1u) ? -cf : cf;
            }
        }

        if (slot < 16) { tabF[obs][slot] = cf; tabU[obs][slot] = cd; }
    } else {
        // non-build waves: finish pooling/Bloch while builders build
        bloch_gather(pv, hof, Xc, Yc, Zc);
    }

    __syncthreads();

    if (builder) bloch_gather(pv, hof, Xc, Yc, Zc);

    // ---- term eval: w = sub>>2 (obs), ls = sub&3; slots ls*4 .. ls*4+3 ----
    const int w = (sub >> 2) & 7, ls = sub & 3;
    float4 cf4 = *reinterpret_cast<const float4*>(&tabF[w][ls * 4]);
    uint4  cd4 = *reinterpret_cast<const uint4 *>(&tabU[w][ls * 4]);
    const float    cfa[4] = { cf4.x, cf4.y, cf4.z, cf4.w };
    const unsigned cda[4] = { cd4.x, cd4.y, cd4.z, cd4.w };

    float acc = 0.f;
#pragma unroll
    for (int kslot = 0; kslot < 4; ++kslot) {
        float p = cfa[kslot];
        unsigned code = cda[kslot];
#define APPLY(J) { int s_ = (int)((code >> (2*J)) & 3u); \
    float f_ = 1.0f; f_ = (s_==1) ? Xc[J] : f_; f_ = (s_==2) ? Yc[J] : f_; \
    f_ = (s_==3) ? Zc[J] : f_;  p *= f_; }
        APPLY(0) APPLY(1) APPLY(2) APPLY(3) APPLY(4) APPLY(5) APPLY(6) APPLY(7)
#undef APPLY
        acc += p;
    }

    // reduce over the 4 slot-lanes (sub bits 0,1) on the VALU pipe
    acc += dppf<0xB1>(acc);
    acc += dppf<0x4E>(acc);
    float ev = acc;                      // all 4 slot-lanes of (half,w) hold ev[w]

    // ---- max-free log_softmax across the 8 observables (sub bits 2,3,4) ----
    // |ev| <= sum|coef| <= 3 (SO(3) rows, <=2 rot expansions) => exp in [.05,20]
    float e  = __expf(ev);
    float se = e;
    se += __shfl_xor(se, 4, 64);
    se += __shfl_xor(se, 8, 64);
    se += __shfl_xor(se, 16, 64);
    float res = ev - __logf(se);

    if (ls == 0 && bidx < bsz)
        out[(size_t)bidx * 8 + w] = res;
}

extern "C" void kernel_launch(void* const* d_in, const int* in_sizes, int n_in,
                              void* d_out, int out_size, void* d_ws, size_t ws_size,
                              hipStream_t stream) {
    const float* x_image   = (const float*)d_in[0];
    const float* theta_rot = (const float*)d_in[1];
    const int*   hardwts   = (const int*)d_in[2];
    float*       out       = (float*)d_out;
    int bsz = in_sizes[0] / 784;   // 8192
    hipLaunchKernelGGL(qnet_one, dim3((bsz + 31) / 32), dim3(1024), 0, stream,
                       x_image, theta_rot, hardwts, out, bsz);
}